// Round 11
// baseline (396.752 us; speedup 1.0000x reference)
//
#include <hip/hip_runtime.h>

#define SEQ 2048
#define NB 4
#define DIN 768
#define EDIM 768
#define NH 12
#define QKVN 2304
#define SCALE 0.125f
#define PADV -1e9f
#define INV12 (0.0833333333f)
#define PSW 520   // Ps row stride in elems
#define VSTR 776  // vals row stride in elems (1552B -> bank offset 4/row)

typedef unsigned short ushort_t;
typedef __attribute__((ext_vector_type(8))) short bf16x8;
typedef __attribute__((ext_vector_type(4))) float f32x4;

__device__ __forceinline__ float bf2f(ushort_t u) {
    union { unsigned int i; float f; } v; v.i = ((unsigned int)u) << 16; return v.f;
}
__device__ __forceinline__ ushort_t f2bf(float f) {
    union { float f; unsigned int i; } v; v.f = f;
    unsigned int r = (v.i + 0x7fffu + ((v.i >> 16) & 1u)) >> 16;
    return (ushort_t)r;
}
__device__ __forceinline__ void gl_lds16(const ushort_t* g, ushort_t* l) {
    __builtin_amdgcn_global_load_lds(
        (const __attribute__((address_space(1))) unsigned int*)(g),
        (__attribute__((address_space(3))) unsigned int*)(l),
        16, 0, 0);
}

// ---------------- fp32 -> bf16 conversion, 3 regions in one launch ----------------
__global__ void cvt3_kernel(const float* __restrict__ s0, int n0,
                            const float* __restrict__ s1, int n1,
                            const float* __restrict__ s2, int n2,
                            ushort_t* __restrict__ d0, ushort_t* __restrict__ d1,
                            ushort_t* __restrict__ d2) {
    int i = blockIdx.x * blockDim.x + threadIdx.x;
    const float* src; ushort_t* dst; int off;
    if (i < n0)               { src = s0; dst = d0; off = i; }
    else if (i < n0 + n1)     { src = s1; dst = d1; off = i - n0; }
    else if (i < n0 + n1 + n2){ src = s2; dst = d2; off = i - n0 - n1; }
    else return;
    float4 f = ((const float4*)src)[off];
    ushort4 u;
    u.x = f2bf(f.x); u.y = f2bf(f.y); u.z = f2bf(f.z); u.w = f2bf(f.w);
    ((ushort4*)dst)[off] = u;
}

// ---------------- 128x128 bf16 MFMA GEMM ----------------
// bf16 out split into qkh[b][h][tok][128] (Q|K) and vt[b][h][d][tok] (transposed V).
__global__ __launch_bounds__(256) void mfma_gemm128(
    const ushort_t* __restrict__ A, const ushort_t* __restrict__ Bw,
    const float* __restrict__ bias,
    ushort_t* __restrict__ qkh, ushort_t* __restrict__ vt, int N, int K)
{
    __shared__ __align__(16) ushort_t Al[128 * 64];
    __shared__ __align__(16) ushort_t Bl[128 * 64];
    const int tid  = threadIdx.x;
    const int w    = tid >> 6;
    const int l    = tid & 63;
    const int quad = l >> 4;
    const int lr   = l & 15;
    const int mw   = (w >> 1) * 64;
    const int nw   = (w & 1) * 64;
    const int bm   = blockIdx.y * 128;
    const int bn   = blockIdx.x * 128;
    const int srow = l >> 3;
    const int sg   = (l & 7) ^ srow;

    f32x4 acc[4][4];
    #pragma unroll
    for (int i = 0; i < 4; ++i)
        #pragma unroll
        for (int j = 0; j < 4; ++j)
            #pragma unroll
            for (int r = 0; r < 4; ++r) acc[i][j][r] = 0.f;

    const ushort_t* ga = A  + (size_t)(bm + w * 32 + srow) * K + sg * 8;
    const ushort_t* gb = Bw + (size_t)(bn + w * 32 + srow) * K + sg * 8;
    ushort_t* la = &Al[(w * 32) * 64];
    ushort_t* lb = &Bl[(w * 32) * 64];

    for (int k0 = 0; k0 < K; k0 += 64) {
        __syncthreads();
        #pragma unroll
        for (int i = 0; i < 4; ++i)
            gl_lds16(ga + (size_t)(i * 8) * K + k0, la + i * 8 * 64);
        #pragma unroll
        for (int i = 0; i < 4; ++i)
            gl_lds16(gb + (size_t)(i * 8) * K + k0, lb + i * 8 * 64);
        __syncthreads();
        #pragma unroll
        for (int s = 0; s < 2; ++s) {
            bf16x8 af[4], bf[4];
            #pragma unroll
            for (int t = 0; t < 4; ++t)
                af[t] = *(const bf16x8*)&Al[(mw + t * 16 + lr) * 64 + (((4 * s + quad) ^ (lr & 7)) * 8)];
            #pragma unroll
            for (int t = 0; t < 4; ++t)
                bf[t] = *(const bf16x8*)&Bl[(nw + t * 16 + lr) * 64 + (((4 * s + quad) ^ (lr & 7)) * 8)];
            #pragma unroll
            for (int mt = 0; mt < 4; ++mt)
                #pragma unroll
                for (int nt = 0; nt < 4; ++nt)
                    acc[mt][nt] = __builtin_amdgcn_mfma_f32_16x16x32_bf16(af[mt], bf[nt], acc[mt][nt], 0, 0, 0);
        }
    }

    #pragma unroll
    for (int nt = 0; nt < 4; ++nt) {
        const int gn = bn + nw + nt * 16 + lr;
        const float bv = bias[gn];
        const int hh  = gn / 192;
        const int rem = gn - hh * 192;
        #pragma unroll
        for (int mt = 0; mt < 4; ++mt) {
            const int gm0 = bm + mw + mt * 16 + quad * 4;
            const int bb  = gm0 >> 11;
            const int tok = gm0 & (SEQ - 1);
            if (rem < 128) {
                #pragma unroll
                for (int r = 0; r < 4; ++r)
                    qkh[((size_t)(bb * NH + hh) * SEQ + tok + r) * 128 + rem] =
                        f2bf(acc[mt][nt][r] + bv);
            } else {
                ushort4 st;
                st.x = f2bf(acc[mt][nt][0] + bv);
                st.y = f2bf(acc[mt][nt][1] + bv);
                st.z = f2bf(acc[mt][nt][2] + bv);
                st.w = f2bf(acc[mt][nt][3] + bv);
                *(ushort4*)&vt[((size_t)(bb * NH + hh) * 64 + (rem - 128)) * SEQ + tok] = st;
            }
        }
    }
}

// ---------------- fused windowed attention + O-projection ----------------
// Grid 512 (XCD-swizzled), 512 thr = 8 waves; waves 0-3 -> even head, 4-7 -> odd.
// values kept in LDS; O = vals @ o_w^T + o_b computed in-block at the end.
__global__ __launch_bounds__(512) void attn_kernel(
    const ushort_t* __restrict__ qkh,   // [NB*NH*SEQ][128] bf16 (Q|K per head)
    const ushort_t* __restrict__ vt,    // [NB*NH*64][SEQ] bf16 (V transposed)
    const float* __restrict__ mmask,    // [NB][SEQ][SEQ]
    const int* __restrict__ pad,        // [NB][SEQ]
    const ushort_t* __restrict__ wob,   // [EDIM][EDIM] bf16 (o_w)
    const float* __restrict__ o_b,      // [EDIM]
    float* __restrict__ out_o,          // [NB*SEQ][EDIM] fp32
    float* __restrict__ attn_out)       // [NB][SEQ][SEQ]
{
    __shared__ __align__(16) ushort_t Ps[2][16 * PSW];   // 33.3 KB
    __shared__ __align__(16) ushort_t vals[16 * VSTR];   // 24.8 KB
    __shared__ float lsump[2][4][16];
    __shared__ int s_cnt[8];
    __shared__ int s_flags[8];
    const int tid  = threadIdx.x;
    const int w    = tid >> 6;       // 0..7
    const int hg   = w >> 2;         // head-group 0/1
    const int ww   = w & 3;          // wave within head
    const int lane = tid & 63;
    const int quad = lane >> 4;
    const int lr   = lane & 15;

    const int lin  = blockIdx.x;
    const int s    = lin & 1;
    const int b    = (lin >> 1) & 3;
    const int i16  = (lin >> 3) + 64 * s;
    const int iq0  = i16 * 16;

    // ---- inline window size (popcount of valid tokens) ----
    {
        int4 pv = *(const int4*)&pad[b * SEQ + tid * 4];
        int c = (pv.x == 0) + (pv.y == 0) + (pv.z == 0) + (pv.w == 0);
        #pragma unroll
        for (int o = 32; o; o >>= 1) c += __shfl_down(c, o, 64);
        if (lane == 0) s_cnt[w] = c;
        if (tid < 8) s_flags[tid] = 0;
    }
    __syncthreads();
    int len = 0;
    #pragma unroll
    for (int k = 0; k < 8; ++k) len += s_cnt[k];
    if (len > 2048) len = 2048;
    int wsz = (int)ceilf((float)len * 10.0f / 100.0f);
    if (wsz < 2) wsz = 2;

    const int jlo  = max(0, iq0 - wsz);
    const int jhi  = min(SEQ - 1, iq0 + 15 + wsz);
    const int jt0  = jlo >> 6;
    const int nch  = (jhi >> 6) - jt0 + 1;   // <= 8
    const int jbase = jt0 << 6;
    const int span  = nch << 6;              // <= 512

    // ---- inline mmask nonzero-tile flags ----
    {
        const float* tp = mmask + ((size_t)b * SEQ + iq0) * SEQ + jbase;
        const int e = tid * 2, row = e >> 6, col = e & 63;
        for (int ci = 0; ci < nch; ++ci) {
            float2 v = *(const float2*)&tp[(size_t)row * SEQ + ci * 64 + col];
            if (__any(v.x != 0.f || v.y != 0.f)) {
                if (lane == 0) atomicOr(&s_flags[ci], 1);
            }
        }
    }

    const int arow = tid & 15;
    const int acg  = tid >> 4;
    float acc[16];
    #pragma unroll
    for (int k = 0; k < 16; ++k) acc[k] = 0.f;
    __syncthreads();   // s_flags ready

    const ushort_t* vhead = vt + (size_t)b * NH * 64 * SEQ;

    for (int hp = 0; hp < NH / 2; ++hp) {
        const int h = hp * 2 + hg;
        const ushort_t* hbase = qkh + (size_t)(b * NH + h) * SEQ * 128;
        const ushort_t* qbase = hbase + (size_t)(iq0 + lr) * 128;
        const bf16x8 qf0 = *(const bf16x8*)(qbase + quad * 8);
        const bf16x8 qf1 = *(const bf16x8*)(qbase + 32 + quad * 8);

        // ---- QK + exp for this wave's chunks (ci = ww, ww+4) ----
        float ls[4] = {0.f, 0.f, 0.f, 0.f};
        #pragma unroll
        for (int cc = 0; cc < 2; ++cc) {
            const int ci = ww + cc * 4;
            if (ci < nch) {
                const int jc = jbase + ci * 64;
                f32x4 s4[4];
                #pragma unroll
                for (int t = 0; t < 4; ++t) {
                    const ushort_t* kr = hbase + (size_t)(jc + t * 16 + lr) * 128 + 64;
                    bf16x8 kf0 = *(const bf16x8*)(kr + quad * 8);
                    bf16x8 kf1 = *(const bf16x8*)(kr + 32 + quad * 8);
                    #pragma unroll
                    for (int r = 0; r < 4; ++r) s4[t][r] = 0.f;
                    s4[t] = __builtin_amdgcn_mfma_f32_16x16x32_bf16(qf0, kf0, s4[t], 0, 0, 0);
                    s4[t] = __builtin_amdgcn_mfma_f32_16x16x32_bf16(qf1, kf1, s4[t], 0, 0, 0);
                }
                const int anym = s_flags[ci];
                #pragma unroll
                for (int t = 0; t < 4; ++t) {
                    const int gj = jc + t * 16 + lr;
                    #pragma unroll
                    for (int r = 0; r < 4; ++r) {
                        const int gi = iq0 + quad * 4 + r;
                        float mm = 0.f;
                        if (anym) mm = mmask[((size_t)b * SEQ + gi) * SEQ + gj];
                        const int dist = gi > gj ? gi - gj : gj - gi;
                        const float p = (dist > wsz) ? 0.f : __expf(fmaf(s4[t][r], SCALE, mm));
                        ls[r] += p;
                        Ps[hg][(quad * 4 + r) * PSW + (ci * 64 + t * 16 + lr)] = f2bf(p);
                    }
                }
            }
        }
        #pragma unroll
        for (int r = 0; r < 4; ++r) {
            #pragma unroll
            for (int m = 8; m; m >>= 1) ls[r] += __shfl_xor(ls[r], m, 16);
        }
        if (lr == 0) {
            #pragma unroll
            for (int r = 0; r < 4; ++r) lsump[hg][ww][quad * 4 + r] = ls[r];
        }
        __syncthreads();

        // ---- head-mean accumulation into registers ----
        if (acg * 16 < span) {
            const float l0 = lsump[0][0][arow] + lsump[0][1][arow] + lsump[0][2][arow] + lsump[0][3][arow];
            const float l1 = lsump[1][0][arow] + lsump[1][1][arow] + lsump[1][2][arow] + lsump[1][3][arow];
            const float sc0 = INV12 / l0;
            const float sc1 = INV12 / l1;
            const ushort_t* p0 = &Ps[0][arow * PSW + acg * 16];
            const ushort_t* p1 = &Ps[1][arow * PSW + acg * 16];
            #pragma unroll
            for (int k = 0; k < 4; ++k) {
                ushort4 u0 = *(const ushort4*)(p0 + k * 4);
                ushort4 u1 = *(const ushort4*)(p1 + k * 4);
                acc[k * 4 + 0] = fmaf(bf2f(u0.x), sc0, fmaf(bf2f(u1.x), sc1, acc[k * 4 + 0]));
                acc[k * 4 + 1] = fmaf(bf2f(u0.y), sc0, fmaf(bf2f(u1.y), sc1, acc[k * 4 + 1]));
                acc[k * 4 + 2] = fmaf(bf2f(u0.z), sc0, fmaf(bf2f(u1.z), sc1, acc[k * 4 + 2]));
                acc[k * 4 + 3] = fmaf(bf2f(u0.w), sc0, fmaf(bf2f(u1.w), sc1, acc[k * 4 + 3]));
            }
        }

        // ---- PV: wave computes head h, d-slice [ww*16, ww*16+16) -> vals (LDS) ----
        {
            f32x4 oacc;
            #pragma unroll
            for (int r = 0; r < 4; ++r) oacc[r] = 0.f;
            const ushort_t* vrow = vhead + (size_t)(h * 64 + ww * 16 + lr) * SEQ + jbase;
            for (int ci = 0; ci < nch; ++ci) {
                const int tok0 = ci * 64;
                #pragma unroll
                for (int s2 = 0; s2 < 2; ++s2) {
                    bf16x8 pa = *(const bf16x8*)&Ps[hg][lr * PSW + tok0 + s2 * 32 + quad * 8];
                    bf16x8 vf = *(const bf16x8*)(vrow + tok0 + s2 * 32 + quad * 8);
                    oacc = __builtin_amdgcn_mfma_f32_16x16x32_bf16(pa, vf, oacc, 0, 0, 0);
                }
            }
            float lr4[4];
            #pragma unroll
            for (int r = 0; r < 4; ++r)
                lr4[r] = lsump[hg][0][quad * 4 + r] + lsump[hg][1][quad * 4 + r] +
                         lsump[hg][2][quad * 4 + r] + lsump[hg][3][quad * 4 + r];
            #pragma unroll
            for (int r = 0; r < 4; ++r)
                vals[(quad * 4 + r) * VSTR + h * 64 + ww * 16 + lr] =
                    f2bf(oacc[r] / lr4[r]);
        }
        __syncthreads();   // Ps/lsump reuse next head pair; vals visible at loop end
    }

    // ---- fused O-projection: O[16][768] = vals @ o_w^T + o_b ----
    // wave w -> cols [w*96, w*96+96) = 6 tiles of 16; K=768 in 4 quarters of 192.
    {
        const int col0 = w * 96;
        f32x4 oaccs[6];
        #pragma unroll
        for (int t = 0; t < 6; ++t)
            #pragma unroll
            for (int r = 0; r < 4; ++r) oaccs[t][r] = 0.f;
        for (int qx = 0; qx < 4; ++qx) {
            bf16x8 af[6];
            #pragma unroll
            for (int ks = 0; ks < 6; ++ks)
                af[ks] = *(const bf16x8*)&vals[lr * VSTR + qx * 192 + ks * 32 + quad * 8];
            #pragma unroll
            for (int t = 0; t < 6; ++t) {
                const ushort_t* bw = wob + (size_t)(col0 + t * 16 + lr) * EDIM + qx * 192 + quad * 8;
                #pragma unroll
                for (int ks = 0; ks < 6; ++ks) {
                    bf16x8 bf = *(const bf16x8*)(bw + ks * 32);
                    oaccs[t] = __builtin_amdgcn_mfma_f32_16x16x32_bf16(af[ks], bf, oaccs[t], 0, 0, 0);
                }
            }
        }
        #pragma unroll
        for (int t = 0; t < 6; ++t) {
            const float bv = o_b[col0 + t * 16 + lr];
            #pragma unroll
            for (int r = 0; r < 4; ++r)
                out_o[(size_t)(b * SEQ + iq0 + quad * 4 + r) * EDIM + col0 + t * 16 + lr] =
                    oaccs[t][r] + bv;
        }
    }

    // ---- write attn_mean ----
    if (acg * 16 < span) {
        float* dst = attn_out + ((size_t)b * SEQ + iq0 + arow) * SEQ + jbase + acg * 16;
        #pragma unroll
        for (int k = 0; k < 4; ++k) {
            float4 v = { acc[k * 4 + 0], acc[k * 4 + 1], acc[k * 4 + 2], acc[k * 4 + 3] };
            *(float4*)(dst + k * 4) = v;
        }
    }
    {
        const int c4lo = jbase >> 2;
        const int c4hi = (jbase + span) >> 2;
        const float4 z = {0.f, 0.f, 0.f, 0.f};
        for (int f = tid; f < 16 * 512; f += 512) {
            const int i  = f >> 9;
            const int c4 = f & 511;
            if (c4 < c4lo || c4 >= c4hi)
                *(float4*)(attn_out + ((size_t)b * SEQ + iq0 + i) * SEQ + c4 * 4) = z;
        }
    }
}

extern "C" void kernel_launch(void* const* d_in, const int* in_sizes, int n_in,
                              void* d_out, int out_size, void* d_ws, size_t ws_size,
                              hipStream_t stream) {
    const float* x      = (const float*)d_in[0];
    const int*   pad    = (const int*)d_in[1];
    const float* mmask  = (const float*)d_in[2];
    const float* qkv_w  = (const float*)d_in[3];
    const float* qkv_b  = (const float*)d_in[4];
    const float* o_w    = (const float*)d_in[5];
    const float* o_b    = (const float*)d_in[6];

    float* out_o    = (float*)d_out;
    float* out_attn = out_o + (size_t)NB * SEQ * EDIM;

    ushort_t* qkh    = (ushort_t*)d_ws;                       // NB*NH*SEQ*128  25.2 MB
    ushort_t* vt     = qkh + (size_t)NB * NH * SEQ * 128;     // NB*NH*64*SEQ   12.6 MB
    ushort_t* xb     = vt + (size_t)NB * NH * 64 * SEQ;       // x bf16         12.6 MB
    ushort_t* wqkvb  = xb + (size_t)NB * SEQ * DIN;           // qkv_w bf16      3.5 MB
    ushort_t* wob    = wqkvb + (size_t)QKVN * DIN;            // o_w bf16        1.2 MB

    const int nx = NB * SEQ * DIN / 4, nw1 = QKVN * DIN / 4, nw2 = EDIM * EDIM / 4;
    cvt3_kernel<<<(nx + nw1 + nw2 + 255) / 256, 256, 0, stream>>>(
        x, nx, qkv_w, nw1, o_w, nw2, xb, wqkvb, wob);

    mfma_gemm128<<<dim3(QKVN / 128, (NB * SEQ) / 128), 256, 0, stream>>>(
        xb, wqkvb, qkv_b, qkh, vt, QKVN, DIN);

    attn_kernel<<<512, 512, 0, stream>>>(
        qkh, vt, mmask, pad, wob, o_b, out_o, out_attn);
}